// Round 2
// baseline (1814.367 us; speedup 1.0000x reference)
//
#include <hip/hip_runtime.h>
#include <hip/hip_bf16.h>
#include <math.h>

#define E_EDGES 50000
#define NN 5000

typedef __hip_bfloat16 bf16;

__device__ __forceinline__ float b2f(bf16 v) { return __bfloat162float(v); }
__device__ __forceinline__ float siluf(float x) { return x / (1.0f + __expf(-x)); }

// ---------------- CG / path constant tables ----------------
// C112[i][j][k]: 1(y,z,x) x 1(y,z,x) -> 2(xy,yz,3z2-1,xz,x2-y2), Frobenius norm 1,
// sign: largest |entry| (1,1,2) positive.
__constant__ int   C112_I[11] = {0,2,0,1,1,2, 0,1,2, 0,2};
__constant__ int   C112_J[11] = {2,0,1,0,2,1, 0,1,2, 0,2};
__constant__ int   C112_K[11] = {0,0,1,1,3,3, 2,2,2, 4,4};
__constant__ float C112_V[11] = {
  0.3162277660168379f, 0.3162277660168379f, 0.3162277660168379f,
  0.3162277660168379f, 0.3162277660168379f, 0.3162277660168379f,
 -0.1825741858350554f, 0.3651483716701107f,-0.1825741858350554f,
 -0.3162277660168379f, 0.3162277660168379f};

// C222: fully symmetric; sign convention: (0,0,2) positive.
__constant__ int   C222_I[25] = {0,0,2, 0,0,1,1,3,3, 1,1,2, 1,1,4, 2, 2,3,3, 2,4,4, 3,3,4};
__constant__ int   C222_J[25] = {0,2,0, 1,3,0,3,0,1, 1,2,1, 1,4,1, 2, 3,2,3, 4,2,4, 3,4,3};
__constant__ int   C222_K[25] = {2,0,0, 3,1,3,0,1,0, 2,1,1, 4,1,1, 2, 3,3,2, 4,4,2, 4,3,3};
__constant__ float C222_V[25] = {
  0.2390457218668787f, 0.2390457218668787f, 0.2390457218668787f,
 -0.2070196678027063f,-0.2070196678027063f,-0.2070196678027063f,
 -0.2070196678027063f,-0.2070196678027063f,-0.2070196678027063f,
 -0.1195228609334394f,-0.1195228609334394f,-0.1195228609334394f,
  0.2070196678027063f, 0.2070196678027063f, 0.2070196678027063f,
 -0.2390457218668787f,
 -0.1195228609334394f,-0.1195228609334394f,-0.1195228609334394f,
  0.2390457218668787f, 0.2390457218668787f, 0.2390457218668787f,
 -0.2070196678027063f,-0.2070196678027063f,-0.2070196678027063f};

// Layer-1 paths (PATHS1 order).
__constant__ int P_M3_[11]   = {32,16, 8,16,32, 8,16, 8,16,32, 8};
__constant__ int P_NK_[11]   = { 1, 3, 5, 3, 1, 5, 3, 5, 3, 1, 5};
__constant__ int P_MOFF_[11] = { 0,32,80,32, 0,80,32,80,32, 0,80};
__constant__ float P_SC_[11] = {
  0.1336306209562122f,   // P0 (0,0,0): 1/sqrt(56)
  0.1178511301977579f,   // P1 (0,1,1): 1/sqrt(72)
  0.125f,                // P2 (0,2,2)
  0.1178511301977579f,   // P3 (1,0,1)
  0.0771516749810460f,   // P4 (1,1,0): 1/sqrt(168)
  0.2795084971874737f,   // P5 (1,1,2): sqrt(5)/8  (raw C112)
  0.2041241452319315f,   // P6 (1,2,1): sqrt(3/72) (raw C121)
  0.125f,                // P7 (2,0,2)
  0.2041241452319315f,   // P8 (2,1,1): raw C211
  0.0597614304667197f,   // P9 (2,2,0): 1/sqrt(280)
  0.2795084971874737f};  // P10 (2,2,2): sqrt(5)/8 (raw C222)

// 54 column-chunks of 64 within the 3456 layer-1 weight dim
__constant__ int CH_P_[54] = {
  0,0,0,0,0,0,0,0,0,0,0,0,0,0,0,0,
  1,1,1,1,1,1,1,1,
  2,2,2,2,
  3,3,3,3,
  4,4,4,4,4,4,4,4,
  5,5,
  6,6,6,6,
  7,
  8,8,
  9,9,9,9,
  10};
__constant__ int CH_U0_[54] = {
  0,2,4,6,8,10,12,14,16,18,20,22,24,26,28,30,
  0,4,8,12,16,20,24,28,
  0,8,16,24,
  0,4,8,12,
  0,2,4,6,8,10,12,14,
  0,8,
  0,4,8,12,
  0,
  0,4,
  0,2,4,6,
  0};

// ---------------- kernels ----------------

__global__ void k_prep(const float* __restrict__ evec, const float* __restrict__ elen,
                       float* __restrict__ shb, float* __restrict__ bc) {
  int e = blockIdx.x * 256 + threadIdx.x;
  if (e >= E_EDGES) return;
  float x = evec[3*e+0], y = evec[3*e+1], z = evec[3*e+2];
  float r = elen[e];
  float inv = 1.0f / (r + 1e-8f);
  float ux = x*inv, uy = y*inv, uz = z*inv;
  const float s3 = 1.7320508075688772f, s5 = 2.2360679774997896f, s15 = 3.8729833462074170f;
  float* sh = shb + (size_t)e*12;
  sh[0] = 1.0f;
  sh[1] = s3*uy; sh[2] = s3*uz; sh[3] = s3*ux;
  sh[4] = s15*ux*uy; sh[5] = s15*uy*uz; sh[6] = 0.5f*s5*(3.0f*uz*uz - 1.0f);
  sh[7] = s15*ux*uz; sh[8] = 0.5f*s15*(ux*ux - uy*uy);
  sh[9] = 0.f; sh[10] = 0.f; sh[11] = 0.f;
  float rr = fmaxf(r, 1e-8f);
  const float pi = 3.14159265358979f;
  float xr = r * 0.2f;
  float cut = (xr < 1.0f) ? 0.5f*(1.0f + cosf(pi*xr)) : 0.0f;
  float fb = pi * 0.2f;
  for (int k = 1; k <= 8; ++k)
    bc[(size_t)e*8 + (k-1)] = sinf(fb*(float)k*r)/rr * cut;
}

__global__ void __launch_bounds__(256) k_rad(
    const float* __restrict__ bc,
    const float* __restrict__ w1, const float* __restrict__ b1,
    const float* __restrict__ w2, const float* __restrict__ b2,
    const float* __restrict__ w01, const float* __restrict__ w11,
    float* __restrict__ q0, float* __restrict__ q1) {
  __shared__ float sA[4][64];
  int tid = threadIdx.x;
  int j = tid >> 6, l = tid & 63;
  int e = blockIdx.x*4 + j;
  const float* bcp = bc + (size_t)e*8;
  float h = b1[l];
  #pragma unroll
  for (int b = 0; b < 8; ++b) h += bcp[b]*w1[b*64+l];
  h = siluf(h);
  sA[j][l] = h;
  __syncthreads();
  float rad = b2[l];
  for (int m = 0; m < 64; ++m) rad += sA[j][m]*w2[m*64+l];
  __syncthreads();
  sA[j][l] = rad;
  __syncthreads();
  float a0 = 0.f, a1 = 0.f;
  for (int m = 0; m < 64; ++m) {
    float rm = sA[j][m];
    a0 += rm*w01[m*64+l];
    a1 += rm*w11[m*64+l];
  }
  q0[(size_t)e*64 + l] = siluf(a0);
  q1[(size_t)e*64 + l] = siluf(a1);
}

__global__ void k_embed(const float* __restrict__ emb, const int* __restrict__ an,
                        float* __restrict__ node0) {
  int i = blockIdx.x*256 + threadIdx.x;   // < 5000*64
  int n = i >> 6, c = i & 63;
  node0[i] = emb[an[n]*64 + c];
}

// reorder wnn0_w2[h, off_b + u*m3 + v]  ->  W0r[u*3584 + h*56 + vp]
__global__ void k_w0r(const float* __restrict__ w, float* __restrict__ W0r) {
  int idx = blockIdx.x*256 + threadIdx.x;
  if (idx >= 64*3584) return;
  int u = idx / 3584, r = idx - u*3584;
  int hh = r / 56, vp = r - hh*56;
  int boff, m3, v;
  if (vp < 32)      { boff = 0;    m3 = 32; v = vp; }
  else if (vp < 48) { boff = 2048; m3 = 16; v = vp - 32; }
  else              { boff = 3072; m3 = 8;  v = vp - 48; }
  W0r[idx] = w[hh*3584 + boff + u*m3 + v];
}

// G0[n, h*56+vp] = sum_u node0[n,u] * W0r[u, h*56+vp]   (M=5000,K=64,N=3584)
__global__ void __launch_bounds__(256) k_g0(const float* __restrict__ node0,
    const float* __restrict__ W0r, bf16* __restrict__ G0) {
  __shared__ float ns[8][64];
  const int tid = threadIdx.x;
  const int col = blockIdx.x*256 + tid;
  const int nb = blockIdx.y*8;
  for (int i = tid; i < 512; i += 256)
    ns[i>>6][i&63] = node0[(size_t)(nb + (i>>6))*64 + (i&63)];
  __syncthreads();
  float acc[8] = {0,0,0,0,0,0,0,0};
  for (int u = 0; u < 64; ++u) {
    float wv = W0r[(size_t)u*3584 + col];
    #pragma unroll
    for (int n = 0; n < 8; ++n) acc[n] += ns[n][u]*wv;
  }
  #pragma unroll
  for (int n = 0; n < 8; ++n)
    G0[(size_t)(nb+n)*3584 + col] = __float2bfloat16(acc[n]);
}

// layer-0 fused message + aggregate: one wave per edge
__global__ void __launch_bounds__(256) k_msg0(
    const float* __restrict__ q0, const bf16* __restrict__ G0,
    const float* __restrict__ shb, const int* __restrict__ ei,
    float* __restrict__ agg0) {
  const int tid = threadIdx.x;
  const int wave = __builtin_amdgcn_readfirstlane(tid >> 6);
  const int lane = tid & 63;
  const int e = blockIdx.x*4 + wave;
  const int src = ei[e], dst = ei[E_EDGES + e];
  const float* qp = q0 + (size_t)e*64;
  const bf16* gp = G0 + (size_t)src*3584 + lane;
  float z = 0.f;
  if (lane < 56) {
    for (int h = 0; h < 64; ++h) z += qp[h]*b2f(gp[h*56]);
  }
  const float c = 0.125f * 0.3162277660168379f;  // (1/8)*inv_sqrt_n
  float* ap = agg0 + (size_t)dst*120;
  const float* sh = shb + (size_t)e*12;
  if (lane < 32) {
    atomicAdd(ap + lane, z*c);
  } else if (lane < 48) {
    int v = lane - 32;
    #pragma unroll
    for (int k = 0; k < 3; ++k) atomicAdd(ap + 32 + v*3 + k, z*sh[1+k]*c);
  } else if (lane < 56) {
    int v = lane - 48;
    #pragma unroll
    for (int k = 0; k < 5; ++k) atomicAdd(ap + 80 + v*5 + k, z*sh[4+k]*c);
  }
}

__global__ void k_node1(const float* __restrict__ agg0, const float* __restrict__ node0,
                        const float* __restrict__ sc00, float* __restrict__ node1) {
  __shared__ float n0[64];
  int n = blockIdx.x, tid = threadIdx.x;
  if (tid < 64) n0[tid] = node0[(size_t)n*64 + tid];
  __syncthreads();
  if (tid >= 120) return;
  float v = agg0[(size_t)n*120 + tid];
  if (tid < 32) {
    float s = 0.f;
    for (int u = 0; u < 64; ++u) s += n0[u]*sc00[u*32 + tid];
    v += s * 0.125f;          // 1/sqrt(64)
    v = siluf(v);
  }
  node1[(size_t)n*120 + tid] = v;
}

#define EPB 32

__global__ void __launch_bounds__(256) k_msg1(
    const float* __restrict__ q1, const float* __restrict__ node1,
    const float* __restrict__ shb, const float* __restrict__ W2f,
    const int* __restrict__ ei, float* __restrict__ agg1) {
  __shared__ float xs[EPB][120];
  __shared__ float shs[EPB][12];
  __shared__ float msgs[EPB][120];
  __shared__ float tch[EPB][40];
  __shared__ float wls[EPB][64];
  __shared__ int srcs[EPB];
  __shared__ int dsts[EPB];
  const int tid = threadIdx.x;
  const int e0 = blockIdx.x * EPB;
  if (tid < EPB) {
    int e = e0 + tid; if (e > E_EDGES-1) e = E_EDGES-1;
    srcs[tid] = ei[e];
    dsts[tid] = ei[E_EDGES + e];
  }
  __syncthreads();
  for (int i = tid; i < EPB*120; i += 256) {
    int e = i/120, c = i - e*120;
    xs[e][c] = node1[(size_t)srcs[e]*120 + c];
    msgs[e][c] = 0.0f;
  }
  for (int i = tid; i < EPB*12; i += 256) {
    int e = i/12, c = i - e*12;
    int eg = e0 + e; if (eg > E_EDGES-1) eg = E_EDGES-1;
    shs[e][c] = shb[(size_t)eg*12 + c];
  }
  const int wave = __builtin_amdgcn_readfirstlane(tid >> 6);
  const int lane = tid & 63;
  const float* qp[8];
  #pragma unroll
  for (int je = 0; je < 8; ++je) {
    int e = e0 + wave*8 + je; if (e > E_EDGES-1) e = E_EDGES-1;
    qp[je] = q1 + (size_t)e*64;
  }
  __syncthreads();

  for (int ch = 0; ch < 54; ++ch) {
    const int p   = CH_P_[ch];
    const int u0  = CH_U0_[ch];
    const int m3  = P_M3_[p];
    const int nk  = P_NK_[p];
    const int upc = 64/m3;
    const int moff = P_MOFF_[p];
    const float sc = P_SC_[p];
    // ---- phase T: t-slice for this chunk's u-range ----
    const int pit = upc*nk;
    for (int i = tid; i < EPB*pit; i += 256) {
      int e = i / pit; int r = i - e*pit;
      int du = r / nk; int k = r - du*nk;
      int u = u0 + du;
      const float* x  = xs[e];
      const float* sh = shs[e];
      float t = 0.0f;
      if (p == 0)      t = x[u];
      else if (p == 1) t = x[u]*sh[1+k];
      else if (p == 2) t = x[u]*sh[4+k];
      else if (p == 3) t = x[32 + u*3 + k];
      else if (p == 4) t = x[32+u*3]*sh[1] + x[32+u*3+1]*sh[2] + x[32+u*3+2]*sh[3];
      else if (p == 5) {
        for (int qe = 0; qe < 11; ++qe) if (C112_K[qe] == k)
          t += C112_V[qe]*x[32 + u*3 + C112_I[qe]]*sh[1 + C112_J[qe]];
      } else if (p == 6) {   // C121[i][j][k] = C112[i][k][j]
        for (int qe = 0; qe < 11; ++qe) if (C112_J[qe] == k)
          t += C112_V[qe]*x[32 + u*3 + C112_I[qe]]*sh[4 + C112_K[qe]];
      } else if (p == 7) t = x[80 + u*5 + k];
      else if (p == 8) {     // C211[i][j][k] = C112[j][k][i]
        for (int qe = 0; qe < 11; ++qe) if (C112_J[qe] == k)
          t += C112_V[qe]*x[80 + u*5 + C112_K[qe]]*sh[1 + C112_I[qe]];
      } else if (p == 9) {
        for (int qe = 0; qe < 5; ++qe) t += x[80 + u*5 + qe]*sh[4 + qe];
      } else {
        for (int qe = 0; qe < 25; ++qe) if (C222_K[qe] == k)
          t += C222_V[qe]*x[80 + u*5 + C222_I[qe]]*sh[4 + C222_J[qe]];
      }
      tch[e][du*nk + k] = t*sc;
    }
    __syncthreads();
    // ---- phase W: w chunk = q1 @ W2 columns [64ch, 64ch+64) ----
    {
      float acc[8] = {0,0,0,0,0,0,0,0};
      const float* wb = W2f + ch*64 + lane;
      for (int h = 0; h < 64; ++h) {
        float wv = wb[(size_t)h*3456];
        #pragma unroll
        for (int je = 0; je < 8; ++je) acc[je] += qp[je][h]*wv;
      }
      #pragma unroll
      for (int je = 0; je < 8; ++je) wls[wave*8+je][lane] = acc[je];
    }
    __syncthreads();
    // ---- phase C: consume w chunk into msg ----
    const int cit = m3*nk;
    for (int i = tid; i < EPB*cit; i += 256) {
      int e = i / cit; int r = i - e*cit;
      int v = r / nk; int k = r - v*nk;
      float a = 0.0f;
      for (int du = 0; du < upc; ++du)
        a += wls[e][du*m3 + v]*tch[e][du*nk + k];
      msgs[e][moff + v*nk + k] += a;
    }
    __syncthreads();
  }
  // epilogue: scatter-add into agg1
  for (int i = tid; i < EPB*120; i += 256) {
    int e = i/120, c = i - e*120;
    if (e0 + e < E_EDGES)
      atomicAdd(&agg1[(size_t)dsts[e]*120 + c], msgs[e][c]*0.3162277660168379f);
  }
}

__global__ void k_out(const float* __restrict__ agg1, const float* __restrict__ node1,
                      const float* __restrict__ sc0e, const float* __restrict__ sc1o,
                      const float* __restrict__ sc2e, float* __restrict__ out) {
  __shared__ float x[120];
  int n = blockIdx.x, tid = threadIdx.x;
  if (tid < 120) x[tid] = node1[(size_t)n*120 + tid];
  __syncthreads();
  if (tid >= 120) return;
  float v = agg1[(size_t)n*120 + tid];
  if (tid < 32) {
    float s = 0.f;
    for (int u = 0; u < 32; ++u) s += x[u]*sc0e[u*32 + tid];
    v += s * 0.1767766952966369f;   // 1/sqrt(32)
  } else if (tid < 80) {
    int jj = tid - 32, vv = jj/3, k = jj - vv*3;
    float s = 0.f;
    for (int u = 0; u < 16; ++u) s += x[32 + u*3 + k]*sc1o[u*16 + vv];
    v += s * 0.25f;                 // 1/sqrt(16)
  } else {
    int jj = tid - 80, vv = jj/5, k = jj - vv*5;
    float s = 0.f;
    for (int u = 0; u < 8; ++u) s += x[80 + u*5 + k]*sc2e[u*8 + vv];
    v += s * 0.3535533905932738f;   // 1/sqrt(8)
  }
  out[(size_t)n*120 + tid] = v;
}

// ---------------- launch ----------------
extern "C" void kernel_launch(void* const* d_in, const int* in_sizes, int n_in,
                              void* d_out, int out_size, void* d_ws, size_t ws_size,
                              hipStream_t stream) {
  const float* embed   = (const float*)d_in[1];
  const float* rad_w1  = (const float*)d_in[2];
  const float* rad_b1  = (const float*)d_in[3];
  const float* rad_w2  = (const float*)d_in[4];
  const float* rad_b2  = (const float*)d_in[5];
  const float* wnn0_w1 = (const float*)d_in[6];
  const float* wnn0_w2 = (const float*)d_in[7];
  const float* wnn1_w1 = (const float*)d_in[8];
  const float* wnn1_w2 = (const float*)d_in[9];
  const float* sc0_0e  = (const float*)d_in[10];
  const float* sc1_0e  = (const float*)d_in[11];
  const float* sc1_1o  = (const float*)d_in[12];
  const float* sc1_2e  = (const float*)d_in[13];
  const float* edge_vec = (const float*)d_in[14];
  const float* edge_len = (const float*)d_in[15];
  const int*  anum    = (const int*)d_in[16];
  const int*  ei      = (const int*)d_in[17];

  float* ws = (float*)d_ws;
  float* shbuf = ws;                    // 50000*12 = 600000
  float* bc    = ws + 600000;           // 50000*8  = 400000
  float* q0    = ws + 1000000;          // 50000*64 = 3200000
  float* q1    = ws + 4200000;          // 3200000
  float* node0 = ws + 7400000;          // 5000*64  = 320000
  float* W0r   = ws + 7720000;          // 229376
  float* agg0  = ws + 7949376;          // 600000
  float* node1 = ws + 8549376;          // 600000
  float* agg1  = ws + 9149376;          // 600000
  bf16*  G0    = (bf16*)(ws + 9749376); // 5000*3584 bf16 = 35.84 MB
  // total ws use ~74.7 MB

  hipMemsetAsync(agg0, 0, 600000*sizeof(float), stream);
  hipMemsetAsync(agg1, 0, 600000*sizeof(float), stream);

  k_prep<<<(E_EDGES+255)/256, 256, 0, stream>>>(edge_vec, edge_len, shbuf, bc);
  k_rad<<<E_EDGES/4, 256, 0, stream>>>(bc, rad_w1, rad_b1, rad_w2, rad_b2,
                                       wnn0_w1, wnn1_w1, q0, q1);
  k_embed<<<(NN*64)/256, 256, 0, stream>>>(embed, anum, node0);
  k_w0r<<<(64*3584+255)/256, 256, 0, stream>>>(wnn0_w2, W0r);
  k_g0<<<dim3(14, NN/8), 256, 0, stream>>>(node0, W0r, G0);
  k_msg0<<<E_EDGES/4, 256, 0, stream>>>(q0, G0, shbuf, ei, agg0);
  k_node1<<<NN, 128, 0, stream>>>(agg0, node0, sc0_0e, node1);
  k_msg1<<<(E_EDGES + EPB - 1)/EPB, 256, 0, stream>>>(q1, node1, shbuf, wnn1_w2, ei, agg1);
  k_out<<<NN, 128, 0, stream>>>(agg1, node1, sc1_0e, sc1_1o, sc1_2e, (float*)d_out);
}

// Round 4
// 1087.435 us; speedup vs baseline: 1.6685x; 1.6685x over previous
//
#include <hip/hip_runtime.h>
#include <hip/hip_bf16.h>
#include <math.h>

#define E_EDGES 50000
#define NN 5000
#define WCH 6250          // edges per layer-1 w chunk (8 chunks)

typedef __hip_bfloat16 bf16;
typedef __attribute__((ext_vector_type(8))) short short8;
typedef __attribute__((ext_vector_type(4))) float f32x4;

__device__ __forceinline__ float b2f(bf16 v) { return __bfloat162float(v); }
__device__ __forceinline__ float siluf(float x) { return x / (1.0f + __expf(-x)); }
__device__ __forceinline__ float us2f(unsigned short u) {
  union { unsigned int i; float f; } c; c.i = ((unsigned int)u) << 16; return c.f;
}

// ---------------- CG / path constant tables ----------------
__constant__ int   C112_I[11] = {0,2,0,1,1,2, 0,1,2, 0,2};
__constant__ int   C112_J[11] = {2,0,1,0,2,1, 0,1,2, 0,2};
__constant__ int   C112_K[11] = {0,0,1,1,3,3, 2,2,2, 4,4};
__constant__ float C112_V[11] = {
  0.3162277660168379f, 0.3162277660168379f, 0.3162277660168379f,
  0.3162277660168379f, 0.3162277660168379f, 0.3162277660168379f,
 -0.1825741858350554f, 0.3651483716701107f,-0.1825741858350554f,
 -0.3162277660168379f, 0.3162277660168379f};

__constant__ int   C222_I[25] = {0,0,2, 0,0,1,1,3,3, 1,1,2, 1,1,4, 2, 2,3,3, 2,4,4, 3,3,4};
__constant__ int   C222_J[25] = {0,2,0, 1,3,0,3,0,1, 1,2,1, 1,4,1, 2, 3,2,3, 4,2,4, 3,4,3};
__constant__ int   C222_K[25] = {2,0,0, 3,1,3,0,1,0, 2,1,1, 4,1,1, 2, 3,3,2, 4,4,2, 4,3,3};
__constant__ float C222_V[25] = {
  0.2390457218668787f, 0.2390457218668787f, 0.2390457218668787f,
 -0.2070196678027063f,-0.2070196678027063f,-0.2070196678027063f,
 -0.2070196678027063f,-0.2070196678027063f,-0.2070196678027063f,
 -0.1195228609334394f,-0.1195228609334394f,-0.1195228609334394f,
  0.2070196678027063f, 0.2070196678027063f, 0.2070196678027063f,
 -0.2390457218668787f,
 -0.1195228609334394f,-0.1195228609334394f,-0.1195228609334394f,
  0.2390457218668787f, 0.2390457218668787f, 0.2390457218668787f,
 -0.2070196678027063f,-0.2070196678027063f,-0.2070196678027063f};

// per-path scale (alpha, diag-CG folded)
__constant__ float P_SC_[11] = {
  0.1336306209562122f, 0.1178511301977579f, 0.125f, 0.1178511301977579f,
  0.0771516749810460f, 0.2795084971874737f, 0.2041241452319315f, 0.125f,
  0.2041241452319315f, 0.0597614304667197f, 0.2795084971874737f};

// ---------------- kernels ----------------

__global__ void k_prep(const float* __restrict__ evec, const float* __restrict__ elen,
                       float* __restrict__ shb, float* __restrict__ bc) {
  int e = blockIdx.x * 256 + threadIdx.x;
  if (e >= E_EDGES) return;
  float x = evec[3*e+0], y = evec[3*e+1], z = evec[3*e+2];
  float r = elen[e];
  float inv = 1.0f / (r + 1e-8f);
  float ux = x*inv, uy = y*inv, uz = z*inv;
  const float s3 = 1.7320508075688772f, s5 = 2.2360679774997896f, s15 = 3.8729833462074170f;
  float* sh = shb + (size_t)e*12;
  sh[0] = 1.0f;
  sh[1] = s3*uy; sh[2] = s3*uz; sh[3] = s3*ux;
  sh[4] = s15*ux*uy; sh[5] = s15*uy*uz; sh[6] = 0.5f*s5*(3.0f*uz*uz - 1.0f);
  sh[7] = s15*ux*uz; sh[8] = 0.5f*s15*(ux*ux - uy*uy);
  sh[9] = 0.f; sh[10] = 0.f; sh[11] = 0.f;
  float rr = fmaxf(r, 1e-8f);
  const float pi = 3.14159265358979f;
  float xr = r * 0.2f;
  float cut = (xr < 1.0f) ? 0.5f*(1.0f + cosf(pi*xr)) : 0.0f;
  float fb = pi * 0.2f;
  for (int k = 1; k <= 8; ++k)
    bc[(size_t)e*8 + (k-1)] = sinf(fb*(float)k*r)/rr * cut;
}

__global__ void __launch_bounds__(256) k_rad(
    const float* __restrict__ bc,
    const float* __restrict__ w1, const float* __restrict__ b1,
    const float* __restrict__ w2, const float* __restrict__ b2,
    const float* __restrict__ w01, const float* __restrict__ w11,
    float* __restrict__ q0, bf16* __restrict__ q1b) {
  __shared__ float sA[4][64];
  int tid = threadIdx.x;
  int j = tid >> 6, l = tid & 63;
  int e = blockIdx.x*4 + j;
  const float* bcp = bc + (size_t)e*8;
  float h = b1[l];
  #pragma unroll
  for (int b = 0; b < 8; ++b) h += bcp[b]*w1[b*64+l];
  h = siluf(h);
  sA[j][l] = h;
  __syncthreads();
  float rad = b2[l];
  for (int m = 0; m < 64; ++m) rad += sA[j][m]*w2[m*64+l];
  __syncthreads();
  sA[j][l] = rad;
  __syncthreads();
  float a0 = 0.f, a1 = 0.f;
  for (int m = 0; m < 64; ++m) {
    float rm = sA[j][m];
    a0 += rm*w01[m*64+l];
    a1 += rm*w11[m*64+l];
  }
  q0[(size_t)e*64 + l] = siluf(a0);
  q1b[(size_t)e*64 + l] = __float2bfloat16(siluf(a1));
}

__global__ void k_embed(const float* __restrict__ emb, const int* __restrict__ an,
                        float* __restrict__ node0) {
  int i = blockIdx.x*256 + threadIdx.x;
  int n = i >> 6, c = i & 63;
  node0[i] = emb[an[n]*64 + c];
}

// reorder wnn0_w2[h, off_b + u*m3 + v]  ->  W0r[u*3584 + h*56 + vp]
__global__ void k_w0r(const float* __restrict__ w, float* __restrict__ W0r) {
  int idx = blockIdx.x*256 + threadIdx.x;
  if (idx >= 64*3584) return;
  int u = idx / 3584, r = idx - u*3584;
  int hh = r / 56, vp = r - hh*56;
  int boff, m3, v;
  if (vp < 32)      { boff = 0;    m3 = 32; v = vp; }
  else if (vp < 48) { boff = 2048; m3 = 16; v = vp - 32; }
  else              { boff = 3072; m3 = 8;  v = vp - 48; }
  W0r[idx] = w[hh*3584 + boff + u*m3 + v];
}

// transpose wnn1_w2 (64 x 3456) -> W2t[n][k] bf16
__global__ void k_w2t(const float* __restrict__ w, bf16* __restrict__ W2t) {
  int idx = blockIdx.x*256 + threadIdx.x;   // 221184
  int n = idx >> 6, k = idx & 63;
  W2t[idx] = __float2bfloat16(w[(size_t)k*3456 + n]);
}

// G0[n, h*56+vp] = sum_u node0[n,u] * W0r[u, h*56+vp]
__global__ void __launch_bounds__(256) k_g0(const float* __restrict__ node0,
    const float* __restrict__ W0r, bf16* __restrict__ G0) {
  __shared__ float ns[8][64];
  const int tid = threadIdx.x;
  const int col = blockIdx.x*256 + tid;
  const int nb = blockIdx.y*8;
  for (int i = tid; i < 512; i += 256)
    ns[i>>6][i&63] = node0[(size_t)(nb + (i>>6))*64 + (i&63)];
  __syncthreads();
  float acc[8] = {0,0,0,0,0,0,0,0};
  for (int u = 0; u < 64; ++u) {
    float wv = W0r[(size_t)u*3584 + col];
    #pragma unroll
    for (int n = 0; n < 8; ++n) acc[n] += ns[n][u]*wv;
  }
  #pragma unroll
  for (int n = 0; n < 8; ++n)
    G0[(size_t)(nb+n)*3584 + col] = __float2bfloat16(acc[n]);
}

// layer-0 fused message + aggregate: one wave per edge
__global__ void __launch_bounds__(256) k_msg0(
    const float* __restrict__ q0, const bf16* __restrict__ G0,
    const float* __restrict__ shb, const int* __restrict__ ei,
    float* __restrict__ agg0) {
  const int tid = threadIdx.x;
  const int wave = __builtin_amdgcn_readfirstlane(tid >> 6);
  const int lane = tid & 63;
  const int e = blockIdx.x*4 + wave;
  const int src = ei[e], dst = ei[E_EDGES + e];
  const float* qp = q0 + (size_t)e*64;
  const bf16* gp = G0 + (size_t)src*3584 + lane;
  float z = 0.f;
  if (lane < 56) {
    for (int h = 0; h < 64; ++h) z += qp[h]*b2f(gp[h*56]);
  }
  const float c = 0.125f * 0.3162277660168379f;
  float* ap = agg0 + (size_t)dst*120;
  const float* sh = shb + (size_t)e*12;
  if (lane < 32) {
    atomicAdd(ap + lane, z*c);
  } else if (lane < 48) {
    int v = lane - 32;
    #pragma unroll
    for (int k = 0; k < 3; ++k) atomicAdd(ap + 32 + v*3 + k, z*sh[1+k]*c);
  } else if (lane < 56) {
    int v = lane - 48;
    #pragma unroll
    for (int k = 0; k < 5; ++k) atomicAdd(ap + 80 + v*5 + k, z*sh[4+k]*c);
  }
}

__global__ void k_node1(const float* __restrict__ agg0, const float* __restrict__ node0,
                        const float* __restrict__ sc00, float* __restrict__ node1) {
  __shared__ float n0[64];
  int n = blockIdx.x, tid = threadIdx.x;
  if (tid < 64) n0[tid] = node0[(size_t)n*64 + tid];
  __syncthreads();
  if (tid >= 120) return;
  float v = agg0[(size_t)n*120 + tid];
  if (tid < 32) {
    float s = 0.f;
    for (int u = 0; u < 64; ++u) s += n0[u]*sc00[u*32 + tid];
    v += s * 0.125f;
    v = siluf(v);
  }
  node1[(size_t)n*120 + tid] = v;
}

// ---- layer-1 w-generation GEMM: w[e, n] = sum_k q1b[e,k] * W2t[n,k]  (MFMA bf16)
// block = 4 waves; wave -> 64-col N-tile; block row-tile = 32 edges
__global__ void __launch_bounds__(256) k_wgemm(
    const bf16* __restrict__ q1b, const bf16* __restrict__ W2t,
    bf16* __restrict__ wout, int e0, int nE) {
  __shared__ short lds[4][32*64];
  const int tid = threadIdx.x;
  const int wid = tid >> 6, lane = tid & 63;
  const int nt = blockIdx.x*4 + wid;
  const int r0 = blockIdx.y*32;
  const int row16 = lane & 15, quad = lane >> 4;

  short8 a[2][2];
  #pragma unroll
  for (int mi = 0; mi < 2; ++mi) {
    int r = r0 + mi*16 + row16;
    int rg = e0 + ((r < nE) ? r : 0);
    const short* ap = (const short*)q1b + (size_t)rg*64 + quad*8;
    a[mi][0] = *(const short8*)(ap);
    a[mi][1] = *(const short8*)(ap + 32);
  }
  if (nt < 54) {
    f32x4 acc[4][2] = {};
    #pragma unroll
    for (int ni = 0; ni < 4; ++ni) {
      int col = nt*64 + ni*16 + row16;
      const short* bp = (const short*)W2t + (size_t)col*64 + quad*8;
      short8 b0 = *(const short8*)(bp);
      short8 b1 = *(const short8*)(bp + 32);
      #pragma unroll
      for (int mi = 0; mi < 2; ++mi) {
        acc[ni][mi] = __builtin_amdgcn_mfma_f32_16x16x32_bf16(a[mi][0], b0, acc[ni][mi], 0,0,0);
        acc[ni][mi] = __builtin_amdgcn_mfma_f32_16x16x32_bf16(a[mi][1], b1, acc[ni][mi], 0,0,0);
      }
    }
    // C layout: col = lane&15, row = quad*4 + reg
    #pragma unroll
    for (int ni = 0; ni < 4; ++ni)
      #pragma unroll
      for (int mi = 0; mi < 2; ++mi)
        #pragma unroll
        for (int rr = 0; rr < 4; ++rr) {
          bf16 hv = __float2bfloat16(acc[ni][mi][rr]);
          lds[wid][(mi*16 + quad*4 + rr)*64 + ni*16 + row16] = *(short*)&hv;
        }
  }
  __syncthreads();
  if (nt < 54) {
    #pragma unroll
    for (int it = 0; it < 4; ++it) {
      int unit = it*64 + lane;           // 256 x 16B units per wave tile
      int rrow = unit >> 3;
      int cu = (unit & 7) * 8;
      int r = r0 + rrow;
      if (r < nE)
        *(uint4*)((short*)wout + (size_t)r*3456 + nt*64 + cu) =
            *(const uint4*)&lds[wid][rrow*64 + cu];
    }
  }
}

// ---- layer-1 consume: per 2 edges, read w row + x + sh, build t, contract, scatter
__global__ void __launch_bounds__(256) k_tp(
    const bf16* __restrict__ wch, const float* __restrict__ node1,
    const float* __restrict__ shb, const int* __restrict__ ei,
    int e0, float* __restrict__ agg1) {
  __shared__ uint4 wq[864];           // 2 rows x 3456 bf16 = 2 x 432 uint4
  __shared__ float tv[2][592];
  __shared__ float xs[2][120];
  __shared__ float shs[2][12];
  const int tid = threadIdx.x;
  const int ebl = blockIdx.x*2;       // chunk-local first edge
  const short* wrow = (const short*)wq;

  for (int i = tid; i < 864; i += 256) {
    int es = i / 432, un = i - es*432;
    wq[i] = ((const uint4*)wch)[(size_t)(ebl + es)*432 + un];
  }
  for (int i = tid; i < 240; i += 256) {
    int es = i / 120, c = i - es*120;
    xs[es][c] = node1[(size_t)ei[e0 + ebl + es]*120 + c];
  }
  if (tid < 24) {
    int es = tid / 12, c = tid - es*12;
    shs[es][c] = shb[(size_t)(e0 + ebl + es)*12 + c];
  }
  __syncthreads();

  // t tensor: offsets p0:0 p1:32 p2:128 p3:288 p4:336 p5:352 p6:432 p7:480 p8:520 p9:544 p10:552 (592)
  for (int i = tid; i < 2*592; i += 256) {
    int es = i / 592; int idx = i - es*592;
    const float* x  = xs[es];
    const float* sh = shs[es];
    float t = 0.0f; int p;
    if (idx < 32)       { p = 0; int u = idx;            t = x[u]; }
    else if (idx < 128) { p = 1; int j = idx-32,  u=j/3, k=j-u*3; t = x[u]*sh[1+k]; }
    else if (idx < 288) { p = 2; int j = idx-128, u=j/5, k=j-u*5; t = x[u]*sh[4+k]; }
    else if (idx < 336) { p = 3; int j = idx-288, u=j/3, k=j-u*3; t = x[32+u*3+k]; }
    else if (idx < 352) { p = 4; int u = idx-336;
      t = x[32+u*3]*sh[1] + x[32+u*3+1]*sh[2] + x[32+u*3+2]*sh[3]; }
    else if (idx < 432) { p = 5; int j = idx-352, u=j/5, k=j-u*5;
      for (int q = 0; q < 11; ++q) if (C112_K[q] == k)
        t += C112_V[q]*x[32+u*3+C112_I[q]]*sh[1+C112_J[q]]; }
    else if (idx < 480) { p = 6; int j = idx-432, u=j/3, k=j-u*3;
      for (int q = 0; q < 11; ++q) if (C112_J[q] == k)
        t += C112_V[q]*x[32+u*3+C112_I[q]]*sh[4+C112_K[q]]; }
    else if (idx < 520) { p = 7; int j = idx-480, u=j/5, k=j-u*5; t = x[80+u*5+k]; }
    else if (idx < 544) { p = 8; int j = idx-520, u=j/3, k=j-u*3;
      for (int q = 0; q < 11; ++q) if (C112_J[q] == k)
        t += C112_V[q]*x[80+u*5+C112_K[q]]*sh[1+C112_I[q]]; }
    else if (idx < 552) { p = 9; int u = idx-544;
      for (int q = 0; q < 5; ++q) t += x[80+u*5+q]*sh[4+q]; }
    else                { p = 10; int j = idx-552, u=j/5, k=j-u*5;
      for (int q = 0; q < 25; ++q) if (C222_K[q] == k)
        t += C222_V[q]*x[80+u*5+C222_I[q]]*sh[4+C222_J[q]]; }
    tv[es][idx] = t * P_SC_[p];
  }
  __syncthreads();

  if (tid < 240) {
    int es = tid / 120, c = tid - es*120;
    const short* w = wrow + es*3456;
    const float* t = tv[es];
    float acc = 0.f;
    if (c < 32) {
      for (int u = 0; u < 32; ++u) acc += us2f((unsigned short)w[u*32+c])      * t[u];
      for (int u = 0; u < 16; ++u) acc += us2f((unsigned short)w[2048+u*32+c]) * t[336+u];
      for (int u = 0; u <  8; ++u) acc += us2f((unsigned short)w[3136+u*32+c]) * t[544+u];
    } else if (c < 80) {
      int j = c-32, v = j/3, k = j-v*3;
      for (int u = 0; u < 32; ++u) acc += us2f((unsigned short)w[1024+u*16+v]) * t[32+u*3+k];
      for (int u = 0; u < 16; ++u) acc += us2f((unsigned short)w[1792+u*16+v]) * t[288+u*3+k];
      for (int u = 0; u < 16; ++u) acc += us2f((unsigned short)w[2688+u*16+v]) * t[432+u*3+k];
      for (int u = 0; u <  8; ++u) acc += us2f((unsigned short)w[3008+u*16+v]) * t[520+u*3+k];
    } else {
      int j = c-80, v = j/5, k = j-v*5;
      for (int u = 0; u < 32; ++u) acc += us2f((unsigned short)w[1536+u*8+v])  * t[128+u*5+k];
      for (int u = 0; u < 16; ++u) acc += us2f((unsigned short)w[2560+u*8+v])  * t[352+u*5+k];
      for (int u = 0; u <  8; ++u) acc += us2f((unsigned short)w[2944+u*8+v])  * t[480+u*5+k];
      for (int u = 0; u <  8; ++u) acc += us2f((unsigned short)w[3392+u*8+v])  * t[552+u*5+k];
    }
    int dst = ei[E_EDGES + e0 + ebl + es];
    atomicAdd(&agg1[(size_t)dst*120 + c], acc * 0.3162277660168379f);
  }
}

__global__ void k_out(const float* __restrict__ agg1, const float* __restrict__ node1,
                      const float* __restrict__ sc0e, const float* __restrict__ sc1o,
                      const float* __restrict__ sc2e, float* __restrict__ out) {
  __shared__ float x[120];
  int n = blockIdx.x, tid = threadIdx.x;
  if (tid < 120) x[tid] = node1[(size_t)n*120 + tid];
  __syncthreads();
  if (tid >= 120) return;
  float v = agg1[(size_t)n*120 + tid];
  if (tid < 32) {
    float s = 0.f;
    for (int u = 0; u < 32; ++u) s += x[u]*sc0e[u*32 + tid];
    v += s * 0.1767766952966369f;
  } else if (tid < 80) {
    int jj = tid - 32, vv = jj/3, k = jj - vv*3;
    float s = 0.f;
    for (int u = 0; u < 16; ++u) s += x[32 + u*3 + k]*sc1o[u*16 + vv];
    v += s * 0.25f;
  } else {
    int jj = tid - 80, vv = jj/5, k = jj - vv*5;
    float s = 0.f;
    for (int u = 0; u < 8; ++u) s += x[80 + u*5 + k]*sc2e[u*8 + vv];
    v += s * 0.3535533905932738f;
  }
  out[(size_t)n*120 + tid] = v;
}

// ---------------- launch ----------------
extern "C" void kernel_launch(void* const* d_in, const int* in_sizes, int n_in,
                              void* d_out, int out_size, void* d_ws, size_t ws_size,
                              hipStream_t stream) {
  const float* embed   = (const float*)d_in[1];
  const float* rad_w1  = (const float*)d_in[2];
  const float* rad_b1  = (const float*)d_in[3];
  const float* rad_w2  = (const float*)d_in[4];
  const float* rad_b2  = (const float*)d_in[5];
  const float* wnn0_w1 = (const float*)d_in[6];
  const float* wnn0_w2 = (const float*)d_in[7];
  const float* wnn1_w1 = (const float*)d_in[8];
  const float* wnn1_w2 = (const float*)d_in[9];
  const float* sc0_0e  = (const float*)d_in[10];
  const float* sc1_0e  = (const float*)d_in[11];
  const float* sc1_1o  = (const float*)d_in[12];
  const float* sc1_2e  = (const float*)d_in[13];
  const float* edge_vec = (const float*)d_in[14];
  const float* edge_len = (const float*)d_in[15];
  const int*  anum    = (const int*)d_in[16];
  const int*  ei      = (const int*)d_in[17];

  float* ws = (float*)d_ws;
  float* shbuf = ws;                      // 600000
  float* bc    = ws + 600000;             // 400000
  bf16*  q1b   = (bf16*)(ws + 1000000);   // 3.2M bf16 = 1.6M f-slots
  float* node0 = ws + 2600000;            // 320000
  float* W0r   = ws + 2920000;            // 229376
  bf16*  W2t   = (bf16*)(ws + 3149376);   // 221184 bf16 = 110592 f-slots
  float* agg0  = ws + 3259968;            // 600000
  float* node1 = ws + 3859968;            // 600000
  float* agg1  = ws + 4459968;            // 600000
  float* q0    = ws + 5059968;            // 3200000
  bf16*  G0    = (bf16*)(ws + 8259968);   // 17.92M bf16 -> end 17219968 (68.9 MB)
  bf16*  wchunk = (bf16*)(ws + 5059968);  // aliases q0+G0 (dead by layer-1); 21.6M bf16 fits

  hipMemsetAsync(agg0, 0, 600000*sizeof(float), stream);
  hipMemsetAsync(agg1, 0, 600000*sizeof(float), stream);

  k_prep<<<(E_EDGES+255)/256, 256, 0, stream>>>(edge_vec, edge_len, shbuf, bc);
  k_rad<<<E_EDGES/4, 256, 0, stream>>>(bc, rad_w1, rad_b1, rad_w2, rad_b2,
                                       wnn0_w1, wnn1_w1, q0, q1b);
  k_embed<<<(NN*64)/256, 256, 0, stream>>>(embed, anum, node0);
  k_w0r<<<(64*3584+255)/256, 256, 0, stream>>>(wnn0_w2, W0r);
  k_w2t<<<(64*3456)/256, 256, 0, stream>>>(wnn1_w2, W2t);
  k_g0<<<dim3(14, NN/8), 256, 0, stream>>>(node0, W0r, G0);
  k_msg0<<<E_EDGES/4, 256, 0, stream>>>(q0, G0, shbuf, ei, agg0);
  k_node1<<<NN, 128, 0, stream>>>(agg0, node0, sc0_0e, node1);

  for (int c = 0; c < 8; ++c) {
    int e0 = c * WCH;
    k_wgemm<<<dim3(14, (WCH+31)/32), 256, 0, stream>>>(q1b, W2t, wchunk, e0, WCH);
    k_tp<<<WCH/2, 256, 0, stream>>>(wchunk, node1, shbuf, ei, e0, agg1);
  }
  k_out<<<NN, 128, 0, stream>>>(agg1, node1, sc1_0e, sc1_1o, sc1_2e, (float*)d_out);
}